// Round 7
// baseline (358.848 us; speedup 1.0000x reference)
//
#include <hip/hip_runtime.h>

#define NC 24  // N*C = 8*3

typedef float f32x4 __attribute__((ext_vector_type(4)));

// ---------- scalar pyrDown point: 5x5 binomial, reflect-101 ----------
__device__ __forceinline__ float pyr_point(const float* ip, int Hi, int Wi, int oy, int ox)
{
    const float k1[5] = {0.0625f, 0.25f, 0.375f, 0.25f, 0.0625f};
    float acc = 0.f;
#pragma unroll
    for (int i = 0; i < 5; ++i) {
        int y = 2 * oy - 2 + i;
        y = (y < 0) ? -y : y;
        y = (y >= Hi) ? (2 * Hi - 2 - y) : y;
        const float* rp = ip + (size_t)y * Wi;
        float r = 0.f;
#pragma unroll
        for (int j = 0; j < 5; ++j) {
            int xx = 2 * ox - 2 + j;
            xx = (xx < 0) ? -xx : xx;
            xx = (xx >= Wi) ? (2 * Wi - 2 - xx) : xx;
            r = fmaf(k1[j], rp[xx], r);
        }
        acc = fmaf(k1[i], r, acc);
    }
    return acc;
}

// ---------- Gaussian blur point, reflect-101 ----------
template <int K>
__device__ __forceinline__ float blur_point(const float* ip, int H, int W, int oy, int ox,
                                            const float* w)
{
    const int R = K / 2;
    float acc = 0.f;
#pragma unroll
    for (int i = 0; i < K; ++i) {
        int y = oy - R + i;
        y = (y < 0) ? -y : y;
        y = (y >= H) ? (2 * H - 2 - y) : y;
        const float* rp = ip + (size_t)y * W;
        float r = 0.f;
#pragma unroll
        for (int j = 0; j < K; ++j) {
            int xx = ox - R + j;
            xx = (xx < 0) ? -xx : xx;
            xx = (xx >= W) ? (2 * W - 2 - xx) : xx;
            r = fmaf(w[j], rp[xx], r);
        }
        acc = fmaf(w[i], r, acc);
    }
    return acc;
}

// ---------- pyrDown v2: tile-to-LDS once (f32x4), separable conv from LDS ----------
template <int HI, int WI>
__global__ void __launch_bounds__(256) pyrdown_v2(
    const float* __restrict__ in, float* __restrict__ out, float scale, float offs)
{
    const int HO = HI / 2, WO = WI / 2;
    __shared__ float tile[35][136];
    __shared__ float vs[16][132];
    const int tid = threadIdx.x;
    const int OX = blockIdx.x * 64;
    const int OY = blockIdx.y * 16;
    const int nc = blockIdx.z;
    const float k1[5] = {0.0625f, 0.25f, 0.375f, 0.25f, 0.0625f};
    const float* ip = in + (size_t)nc * HI * WI;
    const int gx0 = 2 * OX - 4;

    if (gx0 >= 0 && gx0 + 135 < WI) {
        for (int v = tid; v < 35 * 34; v += 256) {
            int r = v / 34, q = v - r * 34;
            int y = 2 * OY - 2 + r;
            y = (y < 0) ? -y : y;
            y = (y >= HI) ? (2 * HI - 2 - y) : y;
            *(f32x4*)&tile[r][4 * q] = *(const f32x4*)&ip[(size_t)y * WI + gx0 + 4 * q];
        }
    } else {
        for (int v = tid; v < 35 * 136; v += 256) {
            int r = v / 136, c = v - r * 136;
            int y = 2 * OY - 2 + r;
            y = (y < 0) ? -y : y;
            y = (y >= HI) ? (2 * HI - 2 - y) : y;
            y = min(max(y, 0), HI - 1);
            int x = gx0 + c;
            x = (x < 0) ? -x : x;
            x = (x >= WI) ? (2 * WI - 2 - x) : x;
            x = min(max(x, 0), WI - 1);
            tile[r][c] = ip[(size_t)y * WI + x];
        }
    }
    __syncthreads();

    for (int v = tid; v < 16 * 132; v += 256) {
        int r = v / 132, c = v - r * 132;
        float acc = k1[0] * tile[2 * r][c + 2];
#pragma unroll
        for (int i = 1; i < 5; ++i) acc = fmaf(k1[i], tile[2 * r + i][c + 2], acc);
        vs[r][c] = acc;
    }
    __syncthreads();

    for (int o = tid; o < 1024; o += 256) {
        int r = o >> 6, c = o & 63;
        int ox = OX + c, oy = OY + r;
        if (ox >= WO || oy >= HO) continue;
        float acc = k1[0] * vs[r][2 * c];
#pragma unroll
        for (int j = 1; j < 5; ++j) acc = fmaf(k1[j], vs[r][2 * c + j], acc);
        out[((size_t)nc * HO + oy) * WO + ox] = fmaf(acc, scale, offs);
    }
}

// ---------- base_kernel: 80 -> {40,20,10,5} + blurs, all in LDS, 1 block/nc ----------
__global__ void __launch_bounds__(512) base_kernel(
    const float* __restrict__ L4g, float* __restrict__ b30g,
    float* __restrict__ b150g, float* __restrict__ b300g)
{
    __shared__ float sL4[80 * 80];
    __shared__ float sL5[40 * 40];
    __shared__ float sL6[20 * 20];
    __shared__ float sL7[10 * 10];
    __shared__ float sL8[5 * 5];
    const int nc = blockIdx.x;
    const int tid = threadIdx.x;

    float w7[7], w9[9];
    {
        float s = 1.4f, s2 = 2.f * s * s, sum = 0.f;
#pragma unroll
        for (int i = 0; i < 7; ++i) { float d = (float)i - 3.f; w7[i] = expf(-(d * d) / s2); sum += w7[i]; }
#pragma unroll
        for (int i = 0; i < 7; ++i) w7[i] /= sum;
        s = 1.7f; s2 = 2.f * s * s; sum = 0.f;
#pragma unroll
        for (int i = 0; i < 9; ++i) { float d = (float)i - 4.f; w9[i] = expf(-(d * d) / s2); sum += w9[i]; }
#pragma unroll
        for (int i = 0; i < 9; ++i) w9[i] /= sum;
    }

    const float* src = L4g + (size_t)nc * 6400;
    for (int i = tid; i < 1600; i += 512)
        *(f32x4*)&sL4[4 * i] = *(const f32x4*)&src[4 * i];
    __syncthreads();
    for (int i = tid; i < 1600; i += 512) {
        int oy = i / 40, ox = i - oy * 40;
        sL5[i] = pyr_point(sL4, 80, 80, oy, ox);
    }
    __syncthreads();
    for (int i = tid; i < 400; i += 512) {
        int oy = i / 20, ox = i - oy * 20;
        sL6[i] = pyr_point(sL5, 40, 40, oy, ox);
    }
    __syncthreads();
    for (int i = tid; i < 100; i += 512) {
        int oy = i / 10, ox = i - oy * 10;
        sL7[i] = pyr_point(sL6, 20, 20, oy, ox);
    }
    __syncthreads();
    for (int i = tid; i < 25; i += 512) {
        int oy = i / 5, ox = i - oy * 5;
        sL8[i] = pyr_point(sL7, 10, 10, oy, ox);
    }
    __syncthreads();
    for (int i = tid; i < 1600; i += 512) {
        int oy = i / 40, ox = i - oy * 40;
        b30g[(size_t)nc * 1600 + i] = blur_point<7>(sL5, 40, 40, oy, ox, w7);
    }
    for (int i = tid; i < 100; i += 512) {
        int oy = i / 10, ox = i - oy * 10;
        b150g[(size_t)nc * 100 + i] = blur_point<9>(sL7, 10, 10, oy, ox, w9);
    }
    for (int i = tid; i < 25; i += 512) {
        int oy = i / 5, ox = i - oy * 5;
        b300g[(size_t)nc * 25 + i] = blur_point<9>(sL8, 5, 5, oy, ox, w9);
    }
}

// ======================= mega_final v3: ladder-free, composed 3x3 stencils =======================
// For each sigma, the full 2x-bilinear upsample chain (clamped at each level) equals a
// single 3-tap-per-axis stencil at the BASE level: taps {m-1,m,m+1}, m = p>>n, weights
// from the parity recurrence over bits of p (exact dyadic values; boundary clamping is
// reproduced by index-clamping the taps — proved by the virtual-row collapse lemma and
// verified against the previous ladder kernel's WP weights).
//   sigma30 : base 40x40,  n=5, table mod 32
//   sigma150: base 10x10,  n=7, table mod 128
//   sigma300: base  5x5,   n=8, table mod 256
__global__ void __launch_bounds__(256) mega_final(
    const float* __restrict__ x,
    const float* __restrict__ b30g,
    const float* __restrict__ b150g,
    const float* __restrict__ b300g,
    float* __restrict__ out)
{
    const int H = 1280, W = 1280;
    __shared__ float W30[32][3];
    __shared__ float W150[128][3];
    __shared__ float W300[256][3];
    __shared__ float P30[3][4][4];   // 40-level patch rows [2*by-1 .. 2*by+2] (clamped)
    __shared__ float P150[3][3][3];  // 10-level rows [(by>>1)-1 .. +1]
    __shared__ float P300[3][3][3];  //  5-level rows [(by>>2)-1 .. +1]

    const int tid = threadIdx.x;
    const int bx = blockIdx.x, by = blockIdx.y, n = blockIdx.z;

    // ---- build composed-weight tables (416 rows, ~1.6 rows/thread) ----
    for (int r = tid; r < 416; r += 256) {
        int idx, nst; float* dst;
        if (r < 32)       { idx = r;       nst = 5; dst = W30[r]; }
        else if (r < 160) { idx = r - 32;  nst = 7; dst = W150[r - 32]; }
        else              { idx = r - 160; nst = 8; dst = W300[r - 160]; }
        float w0 = 0.f, w1 = 1.f, w2 = 0.f;
        for (int k = 0; k < nst; ++k) {
            int c = (idx >> k) & 1;
            float a0 = c ? 0.25f * w0 : fmaf(0.75f, w0, 0.25f * w1);
            float a1 = c ? fmaf(0.75f, w0, fmaf(0.75f, w1, 0.25f * w2))
                         : fmaf(0.25f, w0, fmaf(0.75f, w1, 0.75f * w2));
            float a2 = c ? fmaf(0.25f, w1, 0.75f * w2) : 0.25f * w2;
            w0 = a0; w1 = a1; w2 = a2;
        }
        dst[0] = w0; dst[1] = w1; dst[2] = w2;
    }

    // ---- load base patches (clamp folded into the load; read-time taps never clamp) ----
    {
        const int ay30 = 2 * by - 1, ax30 = 2 * bx - 1;
        const int ay150 = (by >> 1) - 1, ax150 = (bx >> 1) - 1;
        const int ay300 = (by >> 2) - 1, ax300 = (bx >> 2) - 1;
        for (int i = tid; i < 48; i += 256) {             // P30: 3ch x 4x4
            int c = i >> 4, j = i & 15, ry = j >> 2, rx = j & 3;
            int gy = min(max(ay30 + ry, 0), 39), gx = min(max(ax30 + rx, 0), 39);
            P30[c][ry][rx] = b30g[(size_t)(n * 3 + c) * 1600 + gy * 40 + gx];
        }
        for (int i = tid; i < 27; i += 256) {             // P150: 3ch x 3x3
            int c = i / 9, j = i - 9 * c, ry = j / 3, rx = j - 3 * ry;
            int gy = min(max(ay150 + ry, 0), 9), gx = min(max(ax150 + rx, 0), 9);
            P150[c][ry][rx] = b150g[(size_t)(n * 3 + c) * 100 + gy * 10 + gx];
        }
        for (int i = tid; i < 27; i += 256) {             // P300: 3ch x 3x3
            int c = i / 9, j = i - 9 * c, ry = j / 3, rx = j - 3 * ry;
            int gy = min(max(ay300 + ry, 0), 4), gx = min(max(ax300 + rx, 0), 4);
            P300[c][ry][rx] = b300g[(size_t)(n * 3 + c) * 25 + gy * 5 + gx];
        }
    }
    __syncthreads();

    // ---- per-thread: 4x4 px block, 3 channels ----
    const int tyi = tid >> 4, txi = tid & 15;
    const int byi = 16 * by + tyi, bxi = 16 * bx + txi;   // 320-level block index
    // sigma30 patch sub-origin: p>>5 = 2*by + (tyi>=8)  ->  slot base (tyi>=8)
    const int sy30 = tyi >> 3, sx30 = txi >> 3;
    // weight-table row bases (qy/qx added inside; chunks never cross mod boundary)
    const int ryb[3] = {(4 * tyi) & 31, 64 * (by & 1) + 4 * tyi, 64 * (by & 3) + 4 * tyi};
    const int rxb[3] = {(4 * txi) & 31, 64 * (bx & 1) + 4 * txi, 64 * (bx & 3) + 4 * txi};

    float prod[4][4][3];
#pragma unroll
    for (int qy = 0; qy < 4; ++qy)
#pragma unroll
        for (int qx = 0; qx < 4; ++qx)
#pragma unroll
            for (int c = 0; c < 3; ++c) prod[qy][qx][c] = 1.f;

#pragma unroll
    for (int s = 0; s < 3; ++s) {
        float wy[4][3], wx[4][3];
#pragma unroll
        for (int q = 0; q < 4; ++q) {
#pragma unroll
            for (int i = 0; i < 3; ++i) {
                wy[q][i] = (s == 0) ? W30[ryb[0] + q][i]
                         : (s == 1) ? W150[ryb[1] + q][i] : W300[ryb[2] + q][i];
                wx[q][i] = (s == 0) ? W30[rxb[0] + q][i]
                         : (s == 1) ? W150[rxb[1] + q][i] : W300[rxb[2] + q][i];
            }
        }
#pragma unroll
        for (int c = 0; c < 3; ++c) {
            float v[3][3];
#pragma unroll
            for (int i = 0; i < 3; ++i)
#pragma unroll
                for (int j = 0; j < 3; ++j)
                    v[i][j] = (s == 0) ? P30[c][sy30 + i][sx30 + j]
                            : (s == 1) ? P150[c][i][j] : P300[c][i][j];
#pragma unroll
            for (int qy = 0; qy < 4; ++qy) {
                float c0 = fmaf(wy[qy][0], v[0][0], fmaf(wy[qy][1], v[1][0], wy[qy][2] * v[2][0]));
                float c1 = fmaf(wy[qy][0], v[0][1], fmaf(wy[qy][1], v[1][1], wy[qy][2] * v[2][1]));
                float c2 = fmaf(wy[qy][0], v[0][2], fmaf(wy[qy][1], v[1][2], wy[qy][2] * v[2][2]));
#pragma unroll
                for (int qx = 0; qx < 4; ++qx) {
                    float val = fmaf(wx[qx][0], c0, fmaf(wx[qx][1], c1, wx[qx][2] * c2));
                    prod[qy][qx][c] *= (val + 1e-6f);
                }
            }
        }
    }

    // ---- epilogue: load x, MSR math, store ----
    f32x4 xi[3][4];
#pragma unroll
    for (int c = 0; c < 3; ++c)
#pragma unroll
        for (int qy = 0; qy < 4; ++qy)
            xi[c][qy] = __builtin_nontemporal_load(
                (const f32x4*)&x[((size_t)(n * 3 + c) * H + 4 * byi + qy) * W + 4 * bxi]);

    float crcp[4][4];
#pragma unroll
    for (int qy = 0; qy < 4; ++qy)
#pragma unroll
        for (int qx = 0; qx < 4; ++qx) {
            float s = (xi[0][qy][qx] + xi[1][qy][qx] + xi[2][qy][qx]) * 255.f + 3.f;
            crcp[qy][qx] = __fdividef(2.f, s + 1e-6f);
        }

#pragma unroll
    for (int c = 0; c < 3; ++c) {
#pragma unroll
        for (int qy = 0; qy < 4; ++qy) {
            f32x4 o;
#pragma unroll
            for (int qx = 0; qx < 4; ++qx) {
                float img = xi[c][qy][qx] * 255.f + 1.f;
                float a = img + 1e-6f;
                float l2a = __log2f(__fdividef(a * a * a, prod[qy][qx][c]));
                float carg = fmaf(img, crcp[qy][qx], 1.f);
                float l2c = __log2f(carg);
                float e = fmaf(l2a * l2c, 81.55715246f, 128.f);
                e = fminf(fmaxf(e, 0.f), 255.f);
                o[qx] = e * (1.f / 255.f);
            }
            __builtin_nontemporal_store(
                o, (f32x4*)&out[((size_t)(n * 3 + c) * H + 4 * byi + qy) * W + 4 * bxi]);
        }
    }
}

extern "C" void kernel_launch(void* const* d_in, const int* in_sizes, int n_in,
                              void* d_out, int out_size, void* d_ws, size_t ws_size,
                              hipStream_t stream)
{
    const float* x = (const float*)d_in[0];
    float* out = (float*)d_out;
    float* ws = (float*)d_ws;

    size_t off = 0;
    auto alloc = [&](int d) { float* p = ws + off; off += (size_t)NC * d * d; return p; };
    float* L1 = alloc(640);
    float* L2 = alloc(320);
    float* L3 = alloc(160);
    float* L4 = alloc(80);
    float* b30 = alloc(40);
    float* b150 = alloc(10);
    float* b300 = alloc(5);
    (void)ws_size; (void)in_sizes; (void)n_in; (void)out_size;

    dim3 blk(256, 1, 1);

    pyrdown_v2<1280, 1280><<<dim3(10, 40, NC), blk, 0, stream>>>(x,  L1, 255.f, 1.f);
    pyrdown_v2<640, 640><<<dim3(5, 20, NC), blk, 0, stream>>>(L1, L2, 1.f, 0.f);
    pyrdown_v2<320, 320><<<dim3(3, 10, NC), blk, 0, stream>>>(L2, L3, 1.f, 0.f);
    pyrdown_v2<160, 160><<<dim3(2, 5, NC), blk, 0, stream>>>(L3, L4, 1.f, 0.f);
    base_kernel<<<dim3(NC, 1, 1), dim3(512, 1, 1), 0, stream>>>(L4, b30, b150, b300);
    mega_final<<<dim3(20, 20, 8), dim3(256, 1, 1), 0, stream>>>(x, b30, b150, b300, out);
}